// Round 15
// baseline (246.236 us; speedup 1.0000x reference)
//
#include <hip/hip_runtime.h>

#define FD 128      // feature dim (both layers)
#define BSH 7       // log2(nodes per bucket) = 128 nodes/bucket
#define CH 4096     // edges per partition block (391 blocks)
#define CHT 16      // edges per thread (CH / 256)
#define KMAX 512    // max buckets
#define SCAP 8192   // build_kernel LDS edge stage (mean bucket = 4092, max ~4400)
// packed pair: (local_dst << 17) | src   -- requires N <= 131072

typedef __attribute__((ext_vector_type(8))) short bf16x8;
typedef __attribute__((ext_vector_type(4))) float f32x4;

__device__ inline unsigned bfr(float f) {   // fp32 -> bf16 bits, round-nearest-even
    unsigned u = __float_as_uint(f);
    return (u + 0x7FFF + ((u >> 16) & 1)) >> 16;
}
__device__ inline float uplo(unsigned p) { return __uint_as_float(p << 16); }
__device__ inline float uphi(unsigned p) { return __uint_as_float(p & 0xFFFF0000u); }

// ---------------- MFMA bf16 GEMM body (aliased-LDS pointer passed in) ------
// R7-proven lean variant: only B staged in LDS; A fragments loaded directly
// from global. SCALE=false: C = bf16(A @ W) (dis applied later in agg1).

#define APAD 8
#define ASTR (FD + APAD)

template <bool A32, bool SCALE>
__device__ void gemm_body(unsigned short* __restrict__ Bs,
                          const void* __restrict__ Ap,
                          const unsigned short* __restrict__ WT,
                          const float* __restrict__ dis,
                          unsigned short* __restrict__ C, int M, int blk) {
    int tid = threadIdx.x;
    int lane = tid & 63;
    int wave = tid >> 6;
    int quad = lane >> 4;
    int l16 = lane & 15;
    int rowBase = blk * 128;

    #pragma unroll
    for (int p = 0; p < 8; ++p) {
        int r = p * 16 + (tid >> 4);
        int cq = (tid & 15) * 8;
        *(uint4*)&Bs[r * ASTR + cq] = *(const uint4*)&WT[(size_t)r * FD + cq];
    }
    __syncthreads();

    int m0 = wave * 32;
    int r0 = rowBase + m0 + l16;        // a0 fragment row
    int r1 = r0 + 16;                   // a1 fragment row
    f32x4 acc[2][8] = {};
    #pragma unroll
    for (int kt = 0; kt < 4; ++kt) {
        int ko = kt * 32 + quad * 8;
        uint4 va = make_uint4(0u, 0u, 0u, 0u);
        uint4 vb = make_uint4(0u, 0u, 0u, 0u);
        if (A32) {
            const float* A = (const float*)Ap;
            if (r0 < M) {
                const float* a = A + (size_t)r0 * FD + ko;
                float4 f0 = *(const float4*)a;
                float4 f1 = *(const float4*)(a + 4);
                va.x = bfr(f0.x) | (bfr(f0.y) << 16);
                va.y = bfr(f0.z) | (bfr(f0.w) << 16);
                va.z = bfr(f1.x) | (bfr(f1.y) << 16);
                va.w = bfr(f1.z) | (bfr(f1.w) << 16);
            }
            if (r1 < M) {
                const float* a = A + (size_t)r1 * FD + ko;
                float4 f0 = *(const float4*)a;
                float4 f1 = *(const float4*)(a + 4);
                vb.x = bfr(f0.x) | (bfr(f0.y) << 16);
                vb.y = bfr(f0.z) | (bfr(f0.w) << 16);
                vb.z = bfr(f1.x) | (bfr(f1.y) << 16);
                vb.w = bfr(f1.z) | (bfr(f1.w) << 16);
            }
        } else {
            const unsigned short* A = (const unsigned short*)Ap;
            if (r0 < M) va = *(const uint4*)(A + (size_t)r0 * FD + ko);
            if (r1 < M) vb = *(const uint4*)(A + (size_t)r1 * FD + ko);
        }
        bf16x8 a0 = *(bf16x8*)&va;
        bf16x8 a1 = *(bf16x8*)&vb;
        #pragma unroll
        for (int n = 0; n < 8; ++n) {
            bf16x8 b = *(bf16x8*)&Bs[(n * 16 + l16) * ASTR + ko];
            acc[0][n] = __builtin_amdgcn_mfma_f32_16x16x32_bf16(a0, b, acc[0][n], 0, 0, 0);
            acc[1][n] = __builtin_amdgcn_mfma_f32_16x16x32_bf16(a1, b, acc[1][n], 0, 0, 0);
        }
    }

    #pragma unroll
    for (int ms = 0; ms < 2; ++ms) {
        #pragma unroll
        for (int r = 0; r < 4; ++r) {
            int grow = rowBase + m0 + ms * 16 + quad * 4 + r;
            if (grow < M) {
                float dv = SCALE ? dis[grow] : 1.0f;
                #pragma unroll
                for (int n = 0; n < 8; ++n) {
                    float val = SCALE ? (dv * acc[ms][n][r]) : acc[ms][n][r];
                    C[(size_t)grow * FD + n * 16 + l16] = (unsigned short)bfr(val);
                }
            }
        }
    }
}

// ---------------- precision prep (early launch; feeds gemm1 fold) ----------
__global__ void wt_kernel(const float* __restrict__ W1, unsigned short* __restrict__ W1T,
                          const float* __restrict__ W2, unsigned short* __restrict__ W2T) {
    int k = blockIdx.x & (FD - 1);
    int n = threadIdx.x;
    if (blockIdx.x < FD) W1T[n * FD + k] = (unsigned short)bfr(W1[k * FD + n]);
    else                 W2T[n * FD + k] = (unsigned short)bfr(W2[k * FD + n]);
}

// ---------------- fat launch: partition (blocks < PB) + gemm1 (rest) -------
__global__ __launch_bounds__(256) void part_gemm_kernel(
        const int* __restrict__ src, const int* __restrict__ dst,
        int* __restrict__ lstartG, int* __restrict__ total,
        int* __restrict__ pairs, int E, int K, int PB,
        const float* __restrict__ x, const unsigned short* __restrict__ w1t,
        unsigned short* __restrict__ hbuf, int N) {
    __shared__ __align__(16) int smem[8704];   // 34816 B
    int t = threadIdx.x;

    if ((int)blockIdx.x >= PB) {               // gemm1 fold (unscaled output)
        gemm_body<true, false>((unsigned short*)smem, x, w1t, nullptr, hbuf,
                               N, (int)blockIdx.x - PB);
        return;
    }

    int* lcnt   = smem;          // KMAX: counts, then scatter cursor
    int* lstart = smem + 512;    // local exclusive prefix
    int* sm     = smem + 1024;   // 256
    int* staged = smem + 1280;   // CH = 4096

    int base = blockIdx.x * CH;
    int n = min(CH, E - base);

    lcnt[t] = 0; lcnt[t + 256] = 0;
    __syncthreads();

    int pk[CHT]; int bn[CHT];
    #pragma unroll
    for (int j = 0; j < CHT; ++j) {
        int i = t + j * 256;
        bn[j] = -1;
        if (i < n) {
            int d = dst[base + i];
            int s = src[base + i];
            bn[j] = d >> BSH;
            pk[j] = ((d & ((1 << BSH) - 1)) << 17) | s;
            atomicAdd(&lcnt[bn[j]], 1);
        }
    }
    __syncthreads();

    // exclusive scan of 512 bins, 2 consecutive bins per thread
    int c0 = lcnt[2 * t], c1 = lcnt[2 * t + 1];
    int s2 = c0 + c1;
    sm[t] = s2;
    __syncthreads();
    for (int off = 1; off < 256; off <<= 1) {
        int add = (t >= off) ? sm[t - off] : 0;
        __syncthreads();
        sm[t] += add;
        __syncthreads();
    }
    int ex = sm[t] - s2;
    lstart[2 * t] = ex;     lstart[2 * t + 1] = ex + c0;
    lcnt[2 * t]   = ex;     lcnt[2 * t + 1]   = ex + c0;   // cursor
    __syncthreads();

    // scatter chunk into staged[], sorted by bucket
    #pragma unroll
    for (int j = 0; j < CHT; ++j) {
        if (bn[j] >= 0) {
            int pos = atomicAdd(&lcnt[bn[j]], 1);
            staged[pos] = pk[j];
        }
    }
    __syncthreads();

    // sequential coalesced copy-out: this block owns pairs[base .. base+n)
    for (int i = t; i < n; i += 256)
        pairs[base + i] = staged[i];

    // per-block bucket boundaries + bucket totals
    size_t lrow = (size_t)blockIdx.x * (K + 1);
    for (int b = t; b < K; b += 256) {
        lstartG[lrow + b] = lstart[b];
        int c = lcnt[b] - lstart[b];
        if (c) atomicAdd(&total[b], c);
    }
    if (t == 0) lstartG[lrow + K] = n;
}

// merged: blocks [0, nbt) transpose lstartG [PB][K+1] -> lstartT [K+1][PB];
// last block does the 512-wide exclusive scan of total -> bbase (+ rp[N]=E).
__global__ __launch_bounds__(512) void trtot_kernel(
        const int* __restrict__ A, int* __restrict__ B, int R, int C,
        const int* __restrict__ total, int* __restrict__ bbase,
        int* __restrict__ rp, int K, int E, int N, int nbx) {
    __shared__ int tile[32][33];
    int t = threadIdx.x;
    if ((int)blockIdx.x == gridDim.x - 1) {      // totscan body
        __shared__ int sm[512];
        int v = (t < K) ? total[t] : 0;
        sm[t] = v;
        __syncthreads();
        for (int off = 1; off < 512; off <<= 1) {
            int add = (t >= off) ? sm[t - off] : 0;
            __syncthreads();
            sm[t] += add;
            __syncthreads();
        }
        if (t < K) bbase[t] = sm[t] - v;
        if (t == 0) { bbase[K] = E; rp[N] = E; }
        return;
    }
    int c0 = (blockIdx.x % nbx) * 32, r0 = (blockIdx.x / nbx) * 32;
    int tx = t & 31, ty = t >> 5;                // 512 threads: ty in [0,16)
    for (int i = ty; i < 32; i += 16) {
        int r = r0 + i, c = c0 + tx;
        if (r < R && c < C) tile[i][tx] = A[(size_t)r * C + c];
    }
    __syncthreads();
    for (int i = ty; i < 32; i += 16) {
        int c = c0 + i, r = r0 + tx;
        if (c < C && r < R) B[(size_t)c * R + r] = tile[tx][i];
    }
}

// Per-bucket: stage fragments into LDS with FUSED per-wave bin count,
// 512-entry scan ([bin][wave] bin-major), then scatter with per-wave cursors.
__global__ __launch_bounds__(256) void build_kernel(
        const int* __restrict__ pairs, const int* __restrict__ lstartT,
        const int* __restrict__ bbase, int* __restrict__ rp,
        float* __restrict__ dis, int* __restrict__ col, int N, int PB, int K) {
    __shared__ int staged[SCAP];
    __shared__ int lcnt[512];    // [bin*4+wave] counts, then absolute cursor
    __shared__ int pref[512];    // exclusive prefix (bucket-local)
    __shared__ int sm[256];
    int b = blockIdx.x;
    int t = threadIdx.x;
    int wv = t >> 6;
    int nbase = b << BSH;
    int nn = min(1 << BSH, N - nbase);
    int beg = bbase[b];
    int cnt = bbase[b + 1] - beg;

    // fragment descriptors (coalesced reads from transposed lstart; nf <= 2)
    int fp[2], fl0[2], flen[2];
    int nf = 0, mysum = 0;
    for (int p = t; p < PB; p += 256) {
        int l0 = lstartT[(size_t)b * PB + p];
        int l1 = lstartT[(size_t)(b + 1) * PB + p];
        fp[nf] = p; fl0[nf] = l0; flen[nf] = l1 - l0;
        mysum += l1 - l0;
        ++nf;
    }
    // exclusive scan of per-thread sums -> dest offsets in staged
    sm[t] = mysum;
    __syncthreads();
    for (int off = 1; off < 256; off <<= 1) {
        int add = (t >= off) ? sm[t - off] : 0;
        __syncthreads();
        sm[t] += add;
        __syncthreads();
    }
    int o = sm[t] - mysum;

    lcnt[t] = 0; lcnt[t + 256] = 0;
    __syncthreads();

    if (cnt <= SCAP) {   // fast path (always, for Poisson buckets)
        int oo = o;
        for (int f = 0; f < nf; ++f) {
            int gbase = fp[f] * CH + fl0[f];
            for (int i = 0; i < flen[f]; ++i) {
                int p = pairs[gbase + i];
                staged[oo + i] = p;
                atomicAdd(&lcnt[((p >> 17) << 2) | wv], 1);   // fused count
            }
            oo += flen[f];
        }
    } else {             // overflow fallback: count directly from global
        for (int f = 0; f < nf; ++f) {
            int gbase = fp[f] * CH + fl0[f];
            for (int i = 0; i < flen[f]; ++i)
                atomicAdd(&lcnt[((pairs[gbase + i] >> 17) << 2) | wv], 1);
        }
    }
    __syncthreads();

    // exclusive scan of 512 entries (bin-major: bin*4+wave), 2 per thread
    int c0 = lcnt[2 * t], c1 = lcnt[2 * t + 1];
    int s2 = c0 + c1;
    sm[t] = s2;
    __syncthreads();
    for (int off = 1; off < 256; off <<= 1) {
        int add = (t >= off) ? sm[t - off] : 0;
        __syncthreads();
        sm[t] += add;
        __syncthreads();
    }
    int ex = sm[t] - s2;
    pref[2 * t] = ex;  pref[2 * t + 1] = ex + c0;
    __syncthreads();

    // rp/dis per row (row start = plane-0 prefix; deg = row-range length)
    if (t < 128 && t < nn) {
        int rs = pref[t << 2];
        int re = (t < 127) ? pref[(t + 1) << 2] : cnt;
        rp[nbase + t] = beg + rs;
        dis[nbase + t] = rsqrtf((float)(re - rs + 1));  // deg incl. self-loop
    }
    // cursors (absolute)
    lcnt[2 * t]     = beg + pref[2 * t];
    lcnt[2 * t + 1] = beg + pref[2 * t + 1];
    __syncthreads();

    if (cnt <= SCAP) {
        int oo = o;
        for (int f = 0; f < nf; ++f) {
            for (int i = 0; i < flen[f]; ++i) {
                int p = staged[oo + i];
                int pos = atomicAdd(&lcnt[((p >> 17) << 2) | wv], 1);
                col[pos] = p & 0x1FFFF;
            }
            oo += flen[f];
        }
    } else {
        for (int f = 0; f < nf; ++f) {
            int gbase = fp[f] * CH + fl0[f];
            for (int i = 0; i < flen[f]; ++i) {
                int p = pairs[gbase + i];
                int pos = atomicAdd(&lcnt[((p >> 17) << 2) | wv], 1);
                col[pos] = p & 0x1FFFF;
            }
        }
    }
}

__global__ __launch_bounds__(256) void gemm_mfma_bf16(
        const unsigned short* __restrict__ A, const unsigned short* __restrict__ WT,
        const float* __restrict__ dis, unsigned short* __restrict__ C, int M) {
    __shared__ __align__(16) unsigned short Bs[128 * ASTR];
    gemm_body<false, true>(Bs, A, WT, dis, C, M, blockIdx.x);
}

// ---------------- CSR aggregation + bias + ReLU ----------------
// R0-proven structure. ESCALE=1 (agg1): per-edge dis[u] fma (batch 16,
// unchanged from R14). ESCALE=0 (agg2): batch-32 inner loop — R15's
// discriminating test of latency-bound vs line-throughput-floor.

template <bool ESCALE>
__device__ void agg_body(const unsigned* __restrict__ h, const float* __restrict__ dis,
                         const int* __restrict__ rp, const int* __restrict__ col,
                         const float2* __restrict__ bias, void* __restrict__ out,
                         int N, int obf) {
    int v = blockIdx.x * 4 + threadIdx.y;          // blockDim = (64, 4): wave per node
    v = __builtin_amdgcn_readfirstlane(v);         // wave-uniform -> scalar rp/col loads
    if (v >= N) return;
    int t = threadIdx.x;                           // 0..63
    float dv = dis[v];
    size_t vb = (size_t)v * 64 + t;
    unsigned hp = h[vb];                           // self term
    float2 acc;
    if (ESCALE) { acc.x = dv * uplo(hp); acc.y = dv * uphi(hp); }
    else        { acc.x = uplo(hp);      acc.y = uphi(hp); }
    int e = rp[v];
    int end = rp[v + 1];

    if (!ESCALE) {
        for (; e + 32 <= end; e += 32) {           // 32 gathers in flight
            int u[32];
            #pragma unroll
            for (int j = 0; j < 32; ++j) u[j] = col[e + j];
            unsigned p[32];
            #pragma unroll
            for (int j = 0; j < 32; ++j) p[j] = h[(size_t)u[j] * 64 + t];
            #pragma unroll
            for (int j = 0; j < 32; ++j) {
                acc.x += uplo(p[j]); acc.y += uphi(p[j]);
            }
        }
    }
    for (; e + 16 <= end; e += 16) {
        int u[16];
        #pragma unroll
        for (int j = 0; j < 16; ++j) u[j] = col[e + j];   // wave-uniform scalar loads
        float du[16];
        if (ESCALE) {
            #pragma unroll
            for (int j = 0; j < 16; ++j) du[j] = dis[u[j]];
        }
        unsigned p[16];
        #pragma unroll
        for (int j = 0; j < 16; ++j) p[j] = h[(size_t)u[j] * 64 + t];
        #pragma unroll
        for (int j = 0; j < 16; ++j) {
            if (ESCALE) {
                acc.x = fmaf(du[j], uplo(p[j]), acc.x);
                acc.y = fmaf(du[j], uphi(p[j]), acc.y);
            } else {
                acc.x += uplo(p[j]); acc.y += uphi(p[j]);
            }
        }
    }
    for (; e + 4 <= end; e += 4) {
        int u0 = col[e], u1 = col[e + 1], u2 = col[e + 2], u3 = col[e + 3];
        unsigned p0 = h[(size_t)u0 * 64 + t];
        unsigned p1 = h[(size_t)u1 * 64 + t];
        unsigned p2 = h[(size_t)u2 * 64 + t];
        unsigned p3 = h[(size_t)u3 * 64 + t];
        if (ESCALE) {
            float d0 = dis[u0], d1 = dis[u1], d2 = dis[u2], d3 = dis[u3];
            acc.x = fmaf(d0, uplo(p0), acc.x); acc.y = fmaf(d0, uphi(p0), acc.y);
            acc.x = fmaf(d1, uplo(p1), acc.x); acc.y = fmaf(d1, uphi(p1), acc.y);
            acc.x = fmaf(d2, uplo(p2), acc.x); acc.y = fmaf(d2, uphi(p2), acc.y);
            acc.x = fmaf(d3, uplo(p3), acc.x); acc.y = fmaf(d3, uphi(p3), acc.y);
        } else {
            acc.x += uplo(p0); acc.y += uphi(p0);
            acc.x += uplo(p1); acc.y += uphi(p1);
            acc.x += uplo(p2); acc.y += uphi(p2);
            acc.x += uplo(p3); acc.y += uphi(p3);
        }
    }
    for (; e < end; ++e) {
        int u0 = col[e];
        unsigned p = h[(size_t)u0 * 64 + t];
        if (ESCALE) {
            float d0 = dis[u0];
            acc.x = fmaf(d0, uplo(p), acc.x); acc.y = fmaf(d0, uphi(p), acc.y);
        } else {
            acc.x += uplo(p); acc.y += uphi(p);
        }
    }

    float2 bb = bias[t];
    float2 r;
    r.x = fmaxf(fmaf(dv, acc.x, bb.x), 0.0f);
    r.y = fmaxf(fmaf(dv, acc.y, bb.y), 0.0f);
    if (obf) {
        ((unsigned*)out)[vb] = bfr(r.x) | (bfr(r.y) << 16);
    } else {
        ((float2*)out)[vb] = r;
    }
}

__global__ __launch_bounds__(256) void agg_kernel_e(
        const unsigned* __restrict__ h, const float* __restrict__ dis,
        const int* __restrict__ rp, const int* __restrict__ col,
        const float2* __restrict__ bias, void* __restrict__ out, int N, int obf) {
    agg_body<true>(h, dis, rp, col, bias, out, N, obf);
}

__global__ __launch_bounds__(256) void agg_kernel(
        const unsigned* __restrict__ h, const float* __restrict__ dis,
        const int* __restrict__ rp, const int* __restrict__ col,
        const float2* __restrict__ bias, void* __restrict__ out, int N, int obf) {
    agg_body<false>(h, dis, rp, col, bias, out, N, obf);
}

// ---------------- launch ----------------

extern "C" void kernel_launch(void* const* d_in, const int* in_sizes, int n_in,
                              void* d_out, int out_size, void* d_ws, size_t ws_size,
                              hipStream_t stream) {
    const float* x  = (const float*)d_in[0];
    const int*   ei = (const int*)d_in[1];   // [2, E] int32
    const float* W1 = (const float*)d_in[2];
    const float* b1 = (const float*)d_in[3];
    const float* W2 = (const float*)d_in[4];
    const float* b2 = (const float*)d_in[5];

    int N = in_sizes[0] / FD;
    int E = in_sizes[1] / 2;
    const int* src = ei;
    const int* dst = ei + E;
    int K = (N + (1 << BSH) - 1) >> BSH;     // buckets (<= 512 assumed)
    int PB = (E + CH - 1) / CH;              // partition blocks

    char* base = (char*)d_ws;
    size_t off = 0;
    auto align256 = [](size_t v) { return (v + 255) & ~(size_t)255; };
    int*            rp    = (int*)(base + off);            off += align256((size_t)(N + 1) * 4);
    float*          dis   = (float*)(base + off);          off += align256((size_t)N * 4);
    int*            total = (int*)(base + off);            off += align256(512 * 4);
    int*            bbase = (int*)(base + off);            off += align256(513 * 4);
    unsigned short* w1t   = (unsigned short*)(base + off); off += align256((size_t)FD * FD * 2);
    unsigned short* w2t   = (unsigned short*)(base + off); off += align256((size_t)FD * FD * 2);
    int*            col   = (int*)(base + off);            off += align256((size_t)E * 4);
    unsigned short* hbuf  = (unsigned short*)(base + off); off += align256((size_t)N * FD * 2);
    unsigned short* z1    = (unsigned short*)(base + off); off += align256((size_t)N * FD * 2);
    int*            pairs = (int*)(base + off);            off += align256((size_t)E * 4);
    int*            lstartG = (int*)(base + off);          off += align256((size_t)PB * (K + 1) * 4);
    int*            lstartT = (int*)z1;     // overlay: dead before agg1 writes z1
    (void)ws_size; (void)n_in; (void)out_size;

    (void)hipMemsetAsync(total, 0, 512 * 4, stream);
    wt_kernel<<<2 * FD, FD, 0, stream>>>(W1, w1t, W2, w2t);

    int gemmGrid = (N + 127) / 128;
    part_gemm_kernel<<<PB + gemmGrid, 256, 0, stream>>>(
        src, dst, lstartG, total, pairs, E, K, PB, x, w1t, hbuf, N);

    int nbx = (K + 1 + 31) / 32;
    int nby = (PB + 31) / 32;
    trtot_kernel<<<nbx * nby + 1, 512, 0, stream>>>(lstartG, lstartT, PB, K + 1,
                                                    total, bbase, rp, K, E, N, nbx);
    build_kernel<<<K, 256, 0, stream>>>(pairs, lstartT, bbase, rp, dis, col,
                                        N, PB, K);

    dim3 aggBlk(64, 4);
    int aggGrid = (N + 3) / 4;

    agg_kernel_e<<<aggGrid, aggBlk, 0, stream>>>((const unsigned*)hbuf, dis, rp, col,
                                                 (const float2*)b1, z1, N, 1);
    gemm_mfma_bf16<<<gemmGrid, 256, 0, stream>>>(z1, w2t, dis, hbuf, N);
    agg_kernel<<<aggGrid, aggBlk, 0, stream>>>((const unsigned*)hbuf, dis, rp, col,
                                               (const float2*)b2, d_out, N, 0);
}

// Round 16
// 240.006 us; speedup vs baseline: 1.0260x; 1.0260x over previous
//
#include <hip/hip_runtime.h>

#define FD 128      // feature dim (both layers)
#define BSH 7       // log2(nodes per bucket) = 128 nodes/bucket
#define CH 4096     // edges per partition block (391 blocks)
#define CHT 16      // edges per thread (CH / 256)
#define KMAX 512    // max buckets
#define SCAP 8192   // build_kernel LDS edge stage (mean bucket = 4092, max ~4400)
// packed pair: (local_dst << 17) | src   -- requires N <= 131072

typedef __attribute__((ext_vector_type(8))) short bf16x8;
typedef __attribute__((ext_vector_type(4))) float f32x4;

__device__ inline unsigned bfr(float f) {   // fp32 -> bf16 bits, round-nearest-even
    unsigned u = __float_as_uint(f);
    return (u + 0x7FFF + ((u >> 16) & 1)) >> 16;
}
__device__ inline float uplo(unsigned p) { return __uint_as_float(p << 16); }
__device__ inline float uphi(unsigned p) { return __uint_as_float(p & 0xFFFF0000u); }

// ---------------- MFMA bf16 GEMM body (aliased-LDS pointer passed in) ------
// R7-proven lean variant: only B staged in LDS; A fragments loaded directly
// from global. SCALE=false: C = bf16(A @ W); dis applied by build's tail.

#define APAD 8
#define ASTR (FD + APAD)

template <bool A32, bool SCALE>
__device__ void gemm_body(unsigned short* __restrict__ Bs,
                          const void* __restrict__ Ap,
                          const unsigned short* __restrict__ WT,
                          const float* __restrict__ dis,
                          unsigned short* __restrict__ C, int M, int blk) {
    int tid = threadIdx.x;
    int lane = tid & 63;
    int wave = tid >> 6;
    int quad = lane >> 4;
    int l16 = lane & 15;
    int rowBase = blk * 128;

    #pragma unroll
    for (int p = 0; p < 8; ++p) {
        int r = p * 16 + (tid >> 4);
        int cq = (tid & 15) * 8;
        *(uint4*)&Bs[r * ASTR + cq] = *(const uint4*)&WT[(size_t)r * FD + cq];
    }
    __syncthreads();

    int m0 = wave * 32;
    int r0 = rowBase + m0 + l16;        // a0 fragment row
    int r1 = r0 + 16;                   // a1 fragment row
    f32x4 acc[2][8] = {};
    #pragma unroll
    for (int kt = 0; kt < 4; ++kt) {
        int ko = kt * 32 + quad * 8;
        uint4 va = make_uint4(0u, 0u, 0u, 0u);
        uint4 vb = make_uint4(0u, 0u, 0u, 0u);
        if (A32) {
            const float* A = (const float*)Ap;
            if (r0 < M) {
                const float* a = A + (size_t)r0 * FD + ko;
                float4 f0 = *(const float4*)a;
                float4 f1 = *(const float4*)(a + 4);
                va.x = bfr(f0.x) | (bfr(f0.y) << 16);
                va.y = bfr(f0.z) | (bfr(f0.w) << 16);
                va.z = bfr(f1.x) | (bfr(f1.y) << 16);
                va.w = bfr(f1.z) | (bfr(f1.w) << 16);
            }
            if (r1 < M) {
                const float* a = A + (size_t)r1 * FD + ko;
                float4 f0 = *(const float4*)a;
                float4 f1 = *(const float4*)(a + 4);
                vb.x = bfr(f0.x) | (bfr(f0.y) << 16);
                vb.y = bfr(f0.z) | (bfr(f0.w) << 16);
                vb.z = bfr(f1.x) | (bfr(f1.y) << 16);
                vb.w = bfr(f1.z) | (bfr(f1.w) << 16);
            }
        } else {
            const unsigned short* A = (const unsigned short*)Ap;
            if (r0 < M) va = *(const uint4*)(A + (size_t)r0 * FD + ko);
            if (r1 < M) vb = *(const uint4*)(A + (size_t)r1 * FD + ko);
        }
        bf16x8 a0 = *(bf16x8*)&va;
        bf16x8 a1 = *(bf16x8*)&vb;
        #pragma unroll
        for (int n = 0; n < 8; ++n) {
            bf16x8 b = *(bf16x8*)&Bs[(n * 16 + l16) * ASTR + ko];
            acc[0][n] = __builtin_amdgcn_mfma_f32_16x16x32_bf16(a0, b, acc[0][n], 0, 0, 0);
            acc[1][n] = __builtin_amdgcn_mfma_f32_16x16x32_bf16(a1, b, acc[1][n], 0, 0, 0);
        }
    }

    #pragma unroll
    for (int ms = 0; ms < 2; ++ms) {
        #pragma unroll
        for (int r = 0; r < 4; ++r) {
            int grow = rowBase + m0 + ms * 16 + quad * 4 + r;
            if (grow < M) {
                float dv = SCALE ? dis[grow] : 1.0f;
                #pragma unroll
                for (int n = 0; n < 8; ++n) {
                    float val = SCALE ? (dv * acc[ms][n][r]) : acc[ms][n][r];
                    C[(size_t)grow * FD + n * 16 + l16] = (unsigned short)bfr(val);
                }
            }
        }
    }
}

// ---------------- precision prep (early launch; feeds gemm1 fold) ----------
__global__ void wt_kernel(const float* __restrict__ W1, unsigned short* __restrict__ W1T,
                          const float* __restrict__ W2, unsigned short* __restrict__ W2T) {
    int k = blockIdx.x & (FD - 1);
    int n = threadIdx.x;
    if (blockIdx.x < FD) W1T[n * FD + k] = (unsigned short)bfr(W1[k * FD + n]);
    else                 W2T[n * FD + k] = (unsigned short)bfr(W2[k * FD + n]);
}

// ---------------- fat launch: partition (blocks < PB) + gemm1 (rest) -------
__global__ __launch_bounds__(256) void part_gemm_kernel(
        const int* __restrict__ src, const int* __restrict__ dst,
        int* __restrict__ lstartG, int* __restrict__ total,
        int* __restrict__ pairs, int E, int K, int PB,
        const float* __restrict__ x, const unsigned short* __restrict__ w1t,
        unsigned short* __restrict__ hbuf, int N) {
    __shared__ __align__(16) int smem[8704];   // 34816 B
    int t = threadIdx.x;

    if ((int)blockIdx.x >= PB) {               // gemm1 fold (unscaled output)
        gemm_body<true, false>((unsigned short*)smem, x, w1t, nullptr, hbuf,
                               N, (int)blockIdx.x - PB);
        return;
    }

    int* lcnt   = smem;          // KMAX: counts, then scatter cursor
    int* lstart = smem + 512;    // local exclusive prefix
    int* sm     = smem + 1024;   // 256
    int* staged = smem + 1280;   // CH = 4096

    int base = blockIdx.x * CH;
    int n = min(CH, E - base);

    lcnt[t] = 0; lcnt[t + 256] = 0;
    __syncthreads();

    int pk[CHT]; int bn[CHT];
    #pragma unroll
    for (int j = 0; j < CHT; ++j) {
        int i = t + j * 256;
        bn[j] = -1;
        if (i < n) {
            int d = dst[base + i];
            int s = src[base + i];
            bn[j] = d >> BSH;
            pk[j] = ((d & ((1 << BSH) - 1)) << 17) | s;
            atomicAdd(&lcnt[bn[j]], 1);
        }
    }
    __syncthreads();

    // exclusive scan of 512 bins, 2 consecutive bins per thread
    int c0 = lcnt[2 * t], c1 = lcnt[2 * t + 1];
    int s2 = c0 + c1;
    sm[t] = s2;
    __syncthreads();
    for (int off = 1; off < 256; off <<= 1) {
        int add = (t >= off) ? sm[t - off] : 0;
        __syncthreads();
        sm[t] += add;
        __syncthreads();
    }
    int ex = sm[t] - s2;
    lstart[2 * t] = ex;     lstart[2 * t + 1] = ex + c0;
    lcnt[2 * t]   = ex;     lcnt[2 * t + 1]   = ex + c0;   // cursor
    __syncthreads();

    // scatter chunk into staged[], sorted by bucket
    #pragma unroll
    for (int j = 0; j < CHT; ++j) {
        if (bn[j] >= 0) {
            int pos = atomicAdd(&lcnt[bn[j]], 1);
            staged[pos] = pk[j];
        }
    }
    __syncthreads();

    // sequential coalesced copy-out: this block owns pairs[base .. base+n)
    for (int i = t; i < n; i += 256)
        pairs[base + i] = staged[i];

    // per-block bucket boundaries + bucket totals
    size_t lrow = (size_t)blockIdx.x * (K + 1);
    for (int b = t; b < K; b += 256) {
        lstartG[lrow + b] = lstart[b];
        int c = lcnt[b] - lstart[b];
        if (c) atomicAdd(&total[b], c);
    }
    if (t == 0) lstartG[lrow + K] = n;
}

// merged: blocks [0, nbt) transpose lstartG [PB][K+1] -> lstartT [K+1][PB];
// last block does the 512-wide exclusive scan of total -> bbase (+ rp[N]=E).
__global__ __launch_bounds__(512) void trtot_kernel(
        const int* __restrict__ A, int* __restrict__ B, int R, int C,
        const int* __restrict__ total, int* __restrict__ bbase,
        int* __restrict__ rp, int K, int E, int N, int nbx) {
    __shared__ int tile[32][33];
    int t = threadIdx.x;
    if ((int)blockIdx.x == gridDim.x - 1) {      // totscan body
        __shared__ int sm[512];
        int v = (t < K) ? total[t] : 0;
        sm[t] = v;
        __syncthreads();
        for (int off = 1; off < 512; off <<= 1) {
            int add = (t >= off) ? sm[t - off] : 0;
            __syncthreads();
            sm[t] += add;
            __syncthreads();
        }
        if (t < K) bbase[t] = sm[t] - v;
        if (t == 0) { bbase[K] = E; rp[N] = E; }
        return;
    }
    int c0 = (blockIdx.x % nbx) * 32, r0 = (blockIdx.x / nbx) * 32;
    int tx = t & 31, ty = t >> 5;                // 512 threads: ty in [0,16)
    for (int i = ty; i < 32; i += 16) {
        int r = r0 + i, c = c0 + tx;
        if (r < R && c < C) tile[i][tx] = A[(size_t)r * C + c];
    }
    __syncthreads();
    for (int i = ty; i < 32; i += 16) {
        int c = c0 + i, r = r0 + tx;
        if (c < C && r < R) B[(size_t)c * R + r] = tile[tx][i];
    }
}

// Per-bucket: stage fragments into LDS with FUSED per-wave bin count,
// 512-entry scan ([bin][wave] bin-major), scatter with per-wave cursors,
// then a bucket-local TAIL that scales this bucket's hbuf rows by dis
// (race-free: dis for these rows is computed in this very block; hbuf was
// completed by the preceding part_gemm launch). Replaces agg1's per-edge
// dis loads -> both agg launches run the proven 48.5 us plain path.
__global__ __launch_bounds__(256) void build_kernel(
        const int* __restrict__ pairs, const int* __restrict__ lstartT,
        const int* __restrict__ bbase, int* __restrict__ rp,
        float* __restrict__ dis, int* __restrict__ col, int N, int PB, int K,
        unsigned* __restrict__ hbuf) {
    __shared__ int staged[SCAP];
    __shared__ int lcnt[512];    // [bin*4+wave] counts, then absolute cursor
    __shared__ int pref[512];    // exclusive prefix (bucket-local)
    __shared__ int sm[256];      // scan temp; then dis bits for the tail
    int b = blockIdx.x;
    int t = threadIdx.x;
    int wv = t >> 6;
    int nbase = b << BSH;
    int nn = min(1 << BSH, N - nbase);
    int beg = bbase[b];
    int cnt = bbase[b + 1] - beg;

    // fragment descriptors (coalesced reads from transposed lstart; nf <= 2)
    int fp[2], fl0[2], flen[2];
    int nf = 0, mysum = 0;
    for (int p = t; p < PB; p += 256) {
        int l0 = lstartT[(size_t)b * PB + p];
        int l1 = lstartT[(size_t)(b + 1) * PB + p];
        fp[nf] = p; fl0[nf] = l0; flen[nf] = l1 - l0;
        mysum += l1 - l0;
        ++nf;
    }
    // exclusive scan of per-thread sums -> dest offsets in staged
    sm[t] = mysum;
    __syncthreads();
    for (int off = 1; off < 256; off <<= 1) {
        int add = (t >= off) ? sm[t - off] : 0;
        __syncthreads();
        sm[t] += add;
        __syncthreads();
    }
    int o = sm[t] - mysum;

    lcnt[t] = 0; lcnt[t + 256] = 0;
    __syncthreads();

    if (cnt <= SCAP) {   // fast path (always, for Poisson buckets)
        int oo = o;
        for (int f = 0; f < nf; ++f) {
            int gbase = fp[f] * CH + fl0[f];
            for (int i = 0; i < flen[f]; ++i) {
                int p = pairs[gbase + i];
                staged[oo + i] = p;
                atomicAdd(&lcnt[((p >> 17) << 2) | wv], 1);   // fused count
            }
            oo += flen[f];
        }
    } else {             // overflow fallback: count directly from global
        for (int f = 0; f < nf; ++f) {
            int gbase = fp[f] * CH + fl0[f];
            for (int i = 0; i < flen[f]; ++i)
                atomicAdd(&lcnt[((pairs[gbase + i] >> 17) << 2) | wv], 1);
        }
    }
    __syncthreads();

    // exclusive scan of 512 entries (bin-major: bin*4+wave), 2 per thread
    int c0 = lcnt[2 * t], c1 = lcnt[2 * t + 1];
    int s2 = c0 + c1;
    sm[t] = s2;
    __syncthreads();
    for (int off = 1; off < 256; off <<= 1) {
        int add = (t >= off) ? sm[t - off] : 0;
        __syncthreads();
        sm[t] += add;
        __syncthreads();
    }
    int ex = sm[t] - s2;
    pref[2 * t] = ex;  pref[2 * t + 1] = ex + c0;
    __syncthreads();

    // rp/dis per row; stash dis bits in sm[] for the tail (sm is dead now)
    if (t < 128 && t < nn) {
        int rs = pref[t << 2];
        int re = (t < 127) ? pref[(t + 1) << 2] : cnt;
        rp[nbase + t] = beg + rs;
        float dvv = rsqrtf((float)(re - rs + 1));  // deg incl. self-loop
        dis[nbase + t] = dvv;
        sm[t] = __float_as_int(dvv);
    }
    // cursors (absolute)
    lcnt[2 * t]     = beg + pref[2 * t];
    lcnt[2 * t + 1] = beg + pref[2 * t + 1];
    __syncthreads();

    if (cnt <= SCAP) {
        int oo = o;
        for (int f = 0; f < nf; ++f) {
            for (int i = 0; i < flen[f]; ++i) {
                int p = staged[oo + i];
                int pos = atomicAdd(&lcnt[((p >> 17) << 2) | wv], 1);
                col[pos] = p & 0x1FFFF;
            }
            oo += flen[f];
        }
    } else {
        for (int f = 0; f < nf; ++f) {
            int gbase = fp[f] * CH + fl0[f];
            for (int i = 0; i < flen[f]; ++i) {
                int p = pairs[gbase + i];
                int pos = atomicAdd(&lcnt[((p >> 17) << 2) | wv], 1);
                col[pos] = p & 0x1FFFF;
            }
        }
    }

    // bucket-local hbuf scale tail: h''[row] *= dis[row] (bf16 RMW, coalesced)
    {
        unsigned* hb = hbuf + ((size_t)nbase << 6);
        int tot = nn << 6;
        for (int i = t; i < tot; i += 256) {
            float d = __int_as_float(sm[i >> 6]);
            unsigned u = hb[i];
            hb[i] = bfr(d * uplo(u)) | (bfr(d * uphi(u)) << 16);
        }
    }
}

__global__ __launch_bounds__(256) void gemm_mfma_bf16(
        const unsigned short* __restrict__ A, const unsigned short* __restrict__ WT,
        const float* __restrict__ dis, unsigned short* __restrict__ C, int M) {
    __shared__ __align__(16) unsigned short Bs[128 * ASTR];
    gemm_body<false, true>(Bs, A, WT, dis, C, M, blockIdx.x);
}

// ---------------- CSR aggregation + bias + ReLU ----------------
// Round-0 proven form (48.6 us floor, invariant across 9 designs) — UNCHANGED.
// h rows arrive pre-scaled by dis (layer 1: build tail; layer 2: gemm2).

__global__ __launch_bounds__(256) void agg_kernel(
        const unsigned* __restrict__ h, const float* __restrict__ dis,
        const int* __restrict__ rp, const int* __restrict__ col,
        const float2* __restrict__ bias, void* __restrict__ out, int N, int obf) {
    int v = blockIdx.x * 4 + threadIdx.y;          // blockDim = (64, 4): wave per node
    v = __builtin_amdgcn_readfirstlane(v);         // wave-uniform -> scalar rp/col loads
    if (v >= N) return;
    int t = threadIdx.x;                           // 0..63
    float dv = dis[v];
    size_t vb = (size_t)v * 64 + t;
    unsigned hp = h[vb];                           // self term h'[v]
    float2 acc;
    acc.x = uplo(hp); acc.y = uphi(hp);
    int e = rp[v];
    int end = rp[v + 1];

    for (; e + 16 <= end; e += 16) {
        int u[16];
        #pragma unroll
        for (int j = 0; j < 16; ++j) u[j] = col[e + j];   // wave-uniform scalar loads
        unsigned p[16];
        #pragma unroll
        for (int j = 0; j < 16; ++j) p[j] = h[(size_t)u[j] * 64 + t];
        #pragma unroll
        for (int j = 0; j < 16; ++j) {
            acc.x += uplo(p[j]); acc.y += uphi(p[j]);
        }
    }
    for (; e + 4 <= end; e += 4) {
        int u0 = col[e], u1 = col[e + 1], u2 = col[e + 2], u3 = col[e + 3];
        unsigned p0 = h[(size_t)u0 * 64 + t];
        unsigned p1 = h[(size_t)u1 * 64 + t];
        unsigned p2 = h[(size_t)u2 * 64 + t];
        unsigned p3 = h[(size_t)u3 * 64 + t];
        acc.x += uplo(p0); acc.y += uphi(p0);
        acc.x += uplo(p1); acc.y += uphi(p1);
        acc.x += uplo(p2); acc.y += uphi(p2);
        acc.x += uplo(p3); acc.y += uphi(p3);
    }
    for (; e < end; ++e) {
        unsigned p = h[(size_t)col[e] * 64 + t];
        acc.x += uplo(p); acc.y += uphi(p);
    }

    float2 bb = bias[t];
    float2 r;
    r.x = fmaxf(fmaf(dv, acc.x, bb.x), 0.0f);
    r.y = fmaxf(fmaf(dv, acc.y, bb.y), 0.0f);
    if (obf) {
        ((unsigned*)out)[vb] = bfr(r.x) | (bfr(r.y) << 16);
    } else {
        ((float2*)out)[vb] = r;
    }
}

// ---------------- launch ----------------

extern "C" void kernel_launch(void* const* d_in, const int* in_sizes, int n_in,
                              void* d_out, int out_size, void* d_ws, size_t ws_size,
                              hipStream_t stream) {
    const float* x  = (const float*)d_in[0];
    const int*   ei = (const int*)d_in[1];   // [2, E] int32
    const float* W1 = (const float*)d_in[2];
    const float* b1 = (const float*)d_in[3];
    const float* W2 = (const float*)d_in[4];
    const float* b2 = (const float*)d_in[5];

    int N = in_sizes[0] / FD;
    int E = in_sizes[1] / 2;
    const int* src = ei;
    const int* dst = ei + E;
    int K = (N + (1 << BSH) - 1) >> BSH;     // buckets (<= 512 assumed)
    int PB = (E + CH - 1) / CH;              // partition blocks

    char* base = (char*)d_ws;
    size_t off = 0;
    auto align256 = [](size_t v) { return (v + 255) & ~(size_t)255; };
    int*            rp    = (int*)(base + off);            off += align256((size_t)(N + 1) * 4);
    float*          dis   = (float*)(base + off);          off += align256((size_t)N * 4);
    int*            total = (int*)(base + off);            off += align256(512 * 4);
    int*            bbase = (int*)(base + off);            off += align256(513 * 4);
    unsigned short* w1t   = (unsigned short*)(base + off); off += align256((size_t)FD * FD * 2);
    unsigned short* w2t   = (unsigned short*)(base + off); off += align256((size_t)FD * FD * 2);
    int*            col   = (int*)(base + off);            off += align256((size_t)E * 4);
    unsigned short* hbuf  = (unsigned short*)(base + off); off += align256((size_t)N * FD * 2);
    unsigned short* z1    = (unsigned short*)(base + off); off += align256((size_t)N * FD * 2);
    int*            pairs = (int*)(base + off);            off += align256((size_t)E * 4);
    int*            lstartG = (int*)(base + off);          off += align256((size_t)PB * (K + 1) * 4);
    int*            lstartT = (int*)z1;     // overlay: dead before agg1 writes z1
    (void)ws_size; (void)n_in; (void)out_size;

    (void)hipMemsetAsync(total, 0, 512 * 4, stream);
    wt_kernel<<<2 * FD, FD, 0, stream>>>(W1, w1t, W2, w2t);

    int gemmGrid = (N + 127) / 128;
    part_gemm_kernel<<<PB + gemmGrid, 256, 0, stream>>>(
        src, dst, lstartG, total, pairs, E, K, PB, x, w1t, hbuf, N);

    int nbx = (K + 1 + 31) / 32;
    int nby = (PB + 31) / 32;
    trtot_kernel<<<nbx * nby + 1, 512, 0, stream>>>(lstartG, lstartT, PB, K + 1,
                                                    total, bbase, rp, K, E, N, nbx);
    build_kernel<<<K, 256, 0, stream>>>(pairs, lstartT, bbase, rp, dis, col,
                                        N, PB, K, (unsigned*)hbuf);

    dim3 aggBlk(64, 4);
    int aggGrid = (N + 3) / 4;

    agg_kernel<<<aggGrid, aggBlk, 0, stream>>>((const unsigned*)hbuf, dis, rp, col,
                                               (const float2*)b1, z1, N, 1);
    gemm_mfma_bf16<<<gemmGrid, 256, 0, stream>>>(z1, w2t, dis, hbuf, N);
    agg_kernel<<<aggGrid, aggBlk, 0, stream>>>((const unsigned*)hbuf, dis, rp, col,
                                               (const float2*)b2, d_out, N, 0);
}

// Round 17
// 239.065 us; speedup vs baseline: 1.0300x; 1.0039x over previous
//
#include <hip/hip_runtime.h>

#define FD 128      // feature dim (both layers)
#define BSH 7       // log2(nodes per bucket) = 128 nodes/bucket
#define CH 4096     // edges per partition block (391 blocks)
#define CHT 16      // edges per thread (CH / 256)
#define KMAX 512    // max buckets
#define SCAP 8192   // build_kernel LDS edge stage (mean bucket = 4092, max ~4400)
// packed pair: (local_dst << 17) | src   -- requires N <= 131072

typedef __attribute__((ext_vector_type(8))) short bf16x8;
typedef __attribute__((ext_vector_type(4))) float f32x4;

__device__ inline unsigned bfr(float f) {   // fp32 -> bf16 bits, round-nearest-even
    unsigned u = __float_as_uint(f);
    return (u + 0x7FFF + ((u >> 16) & 1)) >> 16;
}
__device__ inline float uplo(unsigned p) { return __uint_as_float(p << 16); }
__device__ inline float uphi(unsigned p) { return __uint_as_float(p & 0xFFFF0000u); }

// inclusive scan of one int per thread across a 256-thread block.
// 6 shfl_up steps in-register + 4-entry cross-wave combine: 2 barriers
// (vs 16 in the ladder scan) -> cuts the co-resident blocks' critical path.
__device__ inline int bscan256(int v, int t, int* ws) {
    int lane = t & 63;
    int w = t >> 6;
    int x = v;
    #pragma unroll
    for (int off = 1; off < 64; off <<= 1) {
        int y = __shfl_up(x, off, 64);
        if (lane >= off) x += y;
    }
    __syncthreads();               // protect ws reuse across consecutive scans
    if (lane == 63) ws[w] = x;
    __syncthreads();
    int add = (w > 0 ? ws[0] : 0) + (w > 1 ? ws[1] : 0) + (w > 2 ? ws[2] : 0);
    return x + add;
}

// ---------------- MFMA bf16 GEMM body (aliased-LDS pointer passed in) ------
// R7-proven lean variant: only B staged in LDS; A fragments loaded directly
// from global. SCALE=false: C = bf16(A @ W); dis applied by build's tail.

#define APAD 8
#define ASTR (FD + APAD)

template <bool A32, bool SCALE>
__device__ void gemm_body(unsigned short* __restrict__ Bs,
                          const void* __restrict__ Ap,
                          const unsigned short* __restrict__ WT,
                          const float* __restrict__ dis,
                          unsigned short* __restrict__ C, int M, int blk) {
    int tid = threadIdx.x;
    int lane = tid & 63;
    int wave = tid >> 6;
    int quad = lane >> 4;
    int l16 = lane & 15;
    int rowBase = blk * 128;

    #pragma unroll
    for (int p = 0; p < 8; ++p) {
        int r = p * 16 + (tid >> 4);
        int cq = (tid & 15) * 8;
        *(uint4*)&Bs[r * ASTR + cq] = *(const uint4*)&WT[(size_t)r * FD + cq];
    }
    __syncthreads();

    int m0 = wave * 32;
    int r0 = rowBase + m0 + l16;        // a0 fragment row
    int r1 = r0 + 16;                   // a1 fragment row
    f32x4 acc[2][8] = {};
    #pragma unroll
    for (int kt = 0; kt < 4; ++kt) {
        int ko = kt * 32 + quad * 8;
        uint4 va = make_uint4(0u, 0u, 0u, 0u);
        uint4 vb = make_uint4(0u, 0u, 0u, 0u);
        if (A32) {
            const float* A = (const float*)Ap;
            if (r0 < M) {
                const float* a = A + (size_t)r0 * FD + ko;
                float4 f0 = *(const float4*)a;
                float4 f1 = *(const float4*)(a + 4);
                va.x = bfr(f0.x) | (bfr(f0.y) << 16);
                va.y = bfr(f0.z) | (bfr(f0.w) << 16);
                va.z = bfr(f1.x) | (bfr(f1.y) << 16);
                va.w = bfr(f1.z) | (bfr(f1.w) << 16);
            }
            if (r1 < M) {
                const float* a = A + (size_t)r1 * FD + ko;
                float4 f0 = *(const float4*)a;
                float4 f1 = *(const float4*)(a + 4);
                vb.x = bfr(f0.x) | (bfr(f0.y) << 16);
                vb.y = bfr(f0.z) | (bfr(f0.w) << 16);
                vb.z = bfr(f1.x) | (bfr(f1.y) << 16);
                vb.w = bfr(f1.z) | (bfr(f1.w) << 16);
            }
        } else {
            const unsigned short* A = (const unsigned short*)Ap;
            if (r0 < M) va = *(const uint4*)(A + (size_t)r0 * FD + ko);
            if (r1 < M) vb = *(const uint4*)(A + (size_t)r1 * FD + ko);
        }
        bf16x8 a0 = *(bf16x8*)&va;
        bf16x8 a1 = *(bf16x8*)&vb;
        #pragma unroll
        for (int n = 0; n < 8; ++n) {
            bf16x8 b = *(bf16x8*)&Bs[(n * 16 + l16) * ASTR + ko];
            acc[0][n] = __builtin_amdgcn_mfma_f32_16x16x32_bf16(a0, b, acc[0][n], 0, 0, 0);
            acc[1][n] = __builtin_amdgcn_mfma_f32_16x16x32_bf16(a1, b, acc[1][n], 0, 0, 0);
        }
    }

    #pragma unroll
    for (int ms = 0; ms < 2; ++ms) {
        #pragma unroll
        for (int r = 0; r < 4; ++r) {
            int grow = rowBase + m0 + ms * 16 + quad * 4 + r;
            if (grow < M) {
                float dv = SCALE ? dis[grow] : 1.0f;
                #pragma unroll
                for (int n = 0; n < 8; ++n) {
                    float val = SCALE ? (dv * acc[ms][n][r]) : acc[ms][n][r];
                    C[(size_t)grow * FD + n * 16 + l16] = (unsigned short)bfr(val);
                }
            }
        }
    }
}

// ---------------- precision prep (early launch; also zeroes total) ---------
__global__ void wt_kernel(const float* __restrict__ W1, unsigned short* __restrict__ W1T,
                          const float* __restrict__ W2, unsigned short* __restrict__ W2T,
                          int* __restrict__ total) {
    int k = blockIdx.x & (FD - 1);
    int n = threadIdx.x;
    if (blockIdx.x == 0) {               // memset fold: total consumed next launch
        #pragma unroll
        for (int j = 0; j < 4; ++j) total[n * 4 + j] = 0;
    }
    if (blockIdx.x < FD) W1T[n * FD + k] = (unsigned short)bfr(W1[k * FD + n]);
    else                 W2T[n * FD + k] = (unsigned short)bfr(W2[k * FD + n]);
}

// ---------------- fat launch: partition (blocks < PB) + gemm1 (rest) -------
__global__ __launch_bounds__(256) void part_gemm_kernel(
        const int* __restrict__ src, const int* __restrict__ dst,
        int* __restrict__ lstartG, int* __restrict__ total,
        int* __restrict__ pairs, int E, int K, int PB,
        const float* __restrict__ x, const unsigned short* __restrict__ w1t,
        unsigned short* __restrict__ hbuf, int N) {
    __shared__ __align__(16) int smem[8704];   // 34816 B
    int t = threadIdx.x;

    if ((int)blockIdx.x >= PB) {               // gemm1 fold (unscaled output)
        gemm_body<true, false>((unsigned short*)smem, x, w1t, nullptr, hbuf,
                               N, (int)blockIdx.x - PB);
        return;
    }

    int* lcnt   = smem;          // KMAX: counts, then scatter cursor
    int* lstart = smem + 512;    // local exclusive prefix
    int* sm     = smem + 1024;   // 256 (scan scratch: 4-entry warpsum)
    int* staged = smem + 1280;   // CH = 4096

    int base = blockIdx.x * CH;
    int n = min(CH, E - base);

    lcnt[t] = 0; lcnt[t + 256] = 0;
    __syncthreads();

    int pk[CHT]; int bn[CHT];
    #pragma unroll
    for (int j = 0; j < CHT; ++j) {
        int i = t + j * 256;
        bn[j] = -1;
        if (i < n) {
            int d = dst[base + i];
            int s = src[base + i];
            bn[j] = d >> BSH;
            pk[j] = ((d & ((1 << BSH) - 1)) << 17) | s;
            atomicAdd(&lcnt[bn[j]], 1);
        }
    }
    __syncthreads();

    // exclusive scan of 512 bins, 2 consecutive bins per thread (shfl scan)
    int c0 = lcnt[2 * t], c1 = lcnt[2 * t + 1];
    int s2 = c0 + c1;
    int incl = bscan256(s2, t, sm);
    int ex = incl - s2;
    __syncthreads();            // lcnt reads above complete before overwrite
    lstart[2 * t] = ex;     lstart[2 * t + 1] = ex + c0;
    lcnt[2 * t]   = ex;     lcnt[2 * t + 1]   = ex + c0;   // cursor
    __syncthreads();

    // scatter chunk into staged[], sorted by bucket
    #pragma unroll
    for (int j = 0; j < CHT; ++j) {
        if (bn[j] >= 0) {
            int pos = atomicAdd(&lcnt[bn[j]], 1);
            staged[pos] = pk[j];
        }
    }
    __syncthreads();

    // sequential coalesced copy-out: this block owns pairs[base .. base+n)
    for (int i = t; i < n; i += 256)
        pairs[base + i] = staged[i];

    // per-block bucket boundaries + bucket totals
    size_t lrow = (size_t)blockIdx.x * (K + 1);
    for (int b = t; b < K; b += 256) {
        lstartG[lrow + b] = lstart[b];
        int c = lcnt[b] - lstart[b];
        if (c) atomicAdd(&total[b], c);
    }
    if (t == 0) lstartG[lrow + K] = n;
}

// merged: blocks [0, nbt) transpose lstartG [PB][K+1] -> lstartT [K+1][PB];
// last block does the 512-wide exclusive scan of total -> bbase (+ rp[N]=E).
__global__ __launch_bounds__(512) void trtot_kernel(
        const int* __restrict__ A, int* __restrict__ B, int R, int C,
        const int* __restrict__ total, int* __restrict__ bbase,
        int* __restrict__ rp, int K, int E, int N, int nbx) {
    __shared__ int tile[32][33];
    int t = threadIdx.x;
    if ((int)blockIdx.x == gridDim.x - 1) {      // totscan body
        __shared__ int sm[512];
        int v = (t < K) ? total[t] : 0;
        sm[t] = v;
        __syncthreads();
        for (int off = 1; off < 512; off <<= 1) {
            int add = (t >= off) ? sm[t - off] : 0;
            __syncthreads();
            sm[t] += add;
            __syncthreads();
        }
        if (t < K) bbase[t] = sm[t] - v;
        if (t == 0) { bbase[K] = E; rp[N] = E; }
        return;
    }
    int c0 = (blockIdx.x % nbx) * 32, r0 = (blockIdx.x / nbx) * 32;
    int tx = t & 31, ty = t >> 5;                // 512 threads: ty in [0,16)
    for (int i = ty; i < 32; i += 16) {
        int r = r0 + i, c = c0 + tx;
        if (r < R && c < C) tile[i][tx] = A[(size_t)r * C + c];
    }
    __syncthreads();
    for (int i = ty; i < 32; i += 16) {
        int c = c0 + i, r = r0 + tx;
        if (c < C && r < R) B[(size_t)c * R + r] = tile[tx][i];
    }
}

// Per-bucket: stage fragments into LDS with FUSED per-wave bin count,
// 512-entry shfl scan, scatter with per-wave cursors, then the bucket-local
// hbuf scale tail (race-free: dis for these rows computed in this block).
__global__ __launch_bounds__(256) void build_kernel(
        const int* __restrict__ pairs, const int* __restrict__ lstartT,
        const int* __restrict__ bbase, int* __restrict__ rp,
        float* __restrict__ dis, int* __restrict__ col, int N, int PB, int K,
        unsigned* __restrict__ hbuf) {
    __shared__ int staged[SCAP];
    __shared__ int lcnt[512];    // [bin*4+wave] counts, then absolute cursor
    __shared__ int pref[512];    // exclusive prefix (bucket-local)
    __shared__ int sm[256];      // scan scratch; then dis bits for the tail
    int b = blockIdx.x;
    int t = threadIdx.x;
    int wv = t >> 6;
    int nbase = b << BSH;
    int nn = min(1 << BSH, N - nbase);
    int beg = bbase[b];
    int cnt = bbase[b + 1] - beg;

    // fragment descriptors (coalesced reads from transposed lstart; nf <= 2)
    int fp[2], fl0[2], flen[2];
    int nf = 0, mysum = 0;
    for (int p = t; p < PB; p += 256) {
        int l0 = lstartT[(size_t)b * PB + p];
        int l1 = lstartT[(size_t)(b + 1) * PB + p];
        fp[nf] = p; fl0[nf] = l0; flen[nf] = l1 - l0;
        mysum += l1 - l0;
        ++nf;
    }
    // exclusive scan of per-thread sums -> dest offsets in staged (shfl scan)
    int o = bscan256(mysum, t, sm) - mysum;

    lcnt[t] = 0; lcnt[t + 256] = 0;
    __syncthreads();

    if (cnt <= SCAP) {   // fast path (always, for Poisson buckets)
        int oo = o;
        for (int f = 0; f < nf; ++f) {
            int gbase = fp[f] * CH + fl0[f];
            for (int i = 0; i < flen[f]; ++i) {
                int p = pairs[gbase + i];
                staged[oo + i] = p;
                atomicAdd(&lcnt[((p >> 17) << 2) | wv], 1);   // fused count
            }
            oo += flen[f];
        }
    } else {             // overflow fallback: count directly from global
        for (int f = 0; f < nf; ++f) {
            int gbase = fp[f] * CH + fl0[f];
            for (int i = 0; i < flen[f]; ++i)
                atomicAdd(&lcnt[((pairs[gbase + i] >> 17) << 2) | wv], 1);
        }
    }
    __syncthreads();

    // exclusive scan of 512 entries (bin-major: bin*4+wave), 2/thread (shfl)
    int c0 = lcnt[2 * t], c1 = lcnt[2 * t + 1];
    int s2 = c0 + c1;
    int incl = bscan256(s2, t, sm);
    int ex = incl - s2;
    pref[2 * t] = ex;  pref[2 * t + 1] = ex + c0;
    __syncthreads();

    // rp/dis per row; stash dis bits in sm[] for the tail (sm is dead now)
    if (t < 128 && t < nn) {
        int rs = pref[t << 2];
        int re = (t < 127) ? pref[(t + 1) << 2] : cnt;
        rp[nbase + t] = beg + rs;
        float dvv = rsqrtf((float)(re - rs + 1));  // deg incl. self-loop
        dis[nbase + t] = dvv;
        sm[t] = __float_as_int(dvv);
    }
    // cursors (absolute)
    lcnt[2 * t]     = beg + pref[2 * t];
    lcnt[2 * t + 1] = beg + pref[2 * t + 1];
    __syncthreads();

    if (cnt <= SCAP) {
        int oo = o;
        for (int f = 0; f < nf; ++f) {
            for (int i = 0; i < flen[f]; ++i) {
                int p = staged[oo + i];
                int pos = atomicAdd(&lcnt[((p >> 17) << 2) | wv], 1);
                col[pos] = p & 0x1FFFF;
            }
            oo += flen[f];
        }
    } else {
        for (int f = 0; f < nf; ++f) {
            int gbase = fp[f] * CH + fl0[f];
            for (int i = 0; i < flen[f]; ++i) {
                int p = pairs[gbase + i];
                int pos = atomicAdd(&lcnt[((p >> 17) << 2) | wv], 1);
                col[pos] = p & 0x1FFFF;
            }
        }
    }

    // bucket-local hbuf scale tail: h''[row] *= dis[row] (bf16 RMW, coalesced)
    {
        unsigned* hb = hbuf + ((size_t)nbase << 6);
        int tot = nn << 6;
        for (int i = t; i < tot; i += 256) {
            float d = __int_as_float(sm[i >> 6]);
            unsigned u = hb[i];
            hb[i] = bfr(d * uplo(u)) | (bfr(d * uphi(u)) << 16);
        }
    }
}

__global__ __launch_bounds__(256) void gemm_mfma_bf16(
        const unsigned short* __restrict__ A, const unsigned short* __restrict__ WT,
        const float* __restrict__ dis, unsigned short* __restrict__ C, int M) {
    __shared__ __align__(16) unsigned short Bs[128 * ASTR];
    gemm_body<false, true>(Bs, A, WT, dis, C, M, blockIdx.x);
}

// ---------------- CSR aggregation + bias + ReLU ----------------
// Round-0 proven form (48.6 us floor, invariant across 9 designs) — UNCHANGED.

__global__ __launch_bounds__(256) void agg_kernel(
        const unsigned* __restrict__ h, const float* __restrict__ dis,
        const int* __restrict__ rp, const int* __restrict__ col,
        const float2* __restrict__ bias, void* __restrict__ out, int N, int obf) {
    int v = blockIdx.x * 4 + threadIdx.y;          // blockDim = (64, 4): wave per node
    v = __builtin_amdgcn_readfirstlane(v);         // wave-uniform -> scalar rp/col loads
    if (v >= N) return;
    int t = threadIdx.x;                           // 0..63
    float dv = dis[v];
    size_t vb = (size_t)v * 64 + t;
    unsigned hp = h[vb];                           // self term h'[v]
    float2 acc;
    acc.x = uplo(hp); acc.y = uphi(hp);
    int e = rp[v];
    int end = rp[v + 1];

    for (; e + 16 <= end; e += 16) {
        int u[16];
        #pragma unroll
        for (int j = 0; j < 16; ++j) u[j] = col[e + j];   // wave-uniform scalar loads
        unsigned p[16];
        #pragma unroll
        for (int j = 0; j < 16; ++j) p[j] = h[(size_t)u[j] * 64 + t];
        #pragma unroll
        for (int j = 0; j < 16; ++j) {
            acc.x += uplo(p[j]); acc.y += uphi(p[j]);
        }
    }
    for (; e + 4 <= end; e += 4) {
        int u0 = col[e], u1 = col[e + 1], u2 = col[e + 2], u3 = col[e + 3];
        unsigned p0 = h[(size_t)u0 * 64 + t];
        unsigned p1 = h[(size_t)u1 * 64 + t];
        unsigned p2 = h[(size_t)u2 * 64 + t];
        unsigned p3 = h[(size_t)u3 * 64 + t];
        acc.x += uplo(p0); acc.y += uphi(p0);
        acc.x += uplo(p1); acc.y += uphi(p1);
        acc.x += uplo(p2); acc.y += uphi(p2);
        acc.x += uplo(p3); acc.y += uphi(p3);
    }
    for (; e < end; ++e) {
        unsigned p = h[(size_t)col[e] * 64 + t];
        acc.x += uplo(p); acc.y += uphi(p);
    }

    float2 bb = bias[t];
    float2 r;
    r.x = fmaxf(fmaf(dv, acc.x, bb.x), 0.0f);
    r.y = fmaxf(fmaf(dv, acc.y, bb.y), 0.0f);
    if (obf) {
        ((unsigned*)out)[vb] = bfr(r.x) | (bfr(r.y) << 16);
    } else {
        ((float2*)out)[vb] = r;
    }
}

// ---------------- launch ----------------

extern "C" void kernel_launch(void* const* d_in, const int* in_sizes, int n_in,
                              void* d_out, int out_size, void* d_ws, size_t ws_size,
                              hipStream_t stream) {
    const float* x  = (const float*)d_in[0];
    const int*   ei = (const int*)d_in[1];   // [2, E] int32
    const float* W1 = (const float*)d_in[2];
    const float* b1 = (const float*)d_in[3];
    const float* W2 = (const float*)d_in[4];
    const float* b2 = (const float*)d_in[5];

    int N = in_sizes[0] / FD;
    int E = in_sizes[1] / 2;
    const int* src = ei;
    const int* dst = ei + E;
    int K = (N + (1 << BSH) - 1) >> BSH;     // buckets (<= 512 assumed)
    int PB = (E + CH - 1) / CH;              // partition blocks

    char* base = (char*)d_ws;
    size_t off = 0;
    auto align256 = [](size_t v) { return (v + 255) & ~(size_t)255; };
    int*            rp    = (int*)(base + off);            off += align256((size_t)(N + 1) * 4);
    float*          dis   = (float*)(base + off);          off += align256((size_t)N * 4);
    int*            total = (int*)(base + off);            off += align256(512 * 4);
    int*            bbase = (int*)(base + off);            off += align256(513 * 4);
    unsigned short* w1t   = (unsigned short*)(base + off); off += align256((size_t)FD * FD * 2);
    unsigned short* w2t   = (unsigned short*)(base + off); off += align256((size_t)FD * FD * 2);
    int*            col   = (int*)(base + off);            off += align256((size_t)E * 4);
    unsigned short* hbuf  = (unsigned short*)(base + off); off += align256((size_t)N * FD * 2);
    unsigned short* z1    = (unsigned short*)(base + off); off += align256((size_t)N * FD * 2);
    int*            pairs = (int*)(base + off);            off += align256((size_t)E * 4);
    int*            lstartG = (int*)(base + off);          off += align256((size_t)PB * (K + 1) * 4);
    int*            lstartT = (int*)z1;     // overlay: dead before agg1 writes z1
    (void)ws_size; (void)n_in; (void)out_size;

    wt_kernel<<<2 * FD, FD, 0, stream>>>(W1, w1t, W2, w2t, total);

    int gemmGrid = (N + 127) / 128;
    part_gemm_kernel<<<PB + gemmGrid, 256, 0, stream>>>(
        src, dst, lstartG, total, pairs, E, K, PB, x, w1t, hbuf, N);

    int nbx = (K + 1 + 31) / 32;
    int nby = (PB + 31) / 32;
    trtot_kernel<<<nbx * nby + 1, 512, 0, stream>>>(lstartG, lstartT, PB, K + 1,
                                                    total, bbase, rp, K, E, N, nbx);
    build_kernel<<<K, 256, 0, stream>>>(pairs, lstartT, bbase, rp, dis, col,
                                        N, PB, K, (unsigned*)hbuf);

    dim3 aggBlk(64, 4);
    int aggGrid = (N + 3) / 4;

    agg_kernel<<<aggGrid, aggBlk, 0, stream>>>((const unsigned*)hbuf, dis, rp, col,
                                               (const float2*)b1, z1, N, 1);
    gemm_mfma_bf16<<<gemmGrid, 256, 0, stream>>>(z1, w2t, dis, hbuf, N);
    agg_kernel<<<aggGrid, aggBlk, 0, stream>>>((const unsigned*)hbuf, dis, rp, col,
                                               (const float2*)b2, d_out, N, 0);
}